// Round 15
// baseline (53.906 us; speedup 1.0000x reference)
//
#include <hip/hip_runtime.h>
#include <hip/hip_fp16.h>

// RotMat forward: 511 rounds of 256 disjoint Givens rotations on rows of a
// [512, 1024] fp32 matrix (round-robin tournament schedule).
//
// Position-space: position k pairs with 511-k every round; between rounds a
// fixed cyclic shift. After 511 rounds the permutation is identity.
//
// Ladder: R0 177us -> R13 45.7us (DPP shifts, LDS triple-buffer glds16,
// pinned asm ds_read_b128 + counted lgkm, f16-packed coeffs). Model after
// R13: ~90cy VALU + ~48cy LDS pipe + ~80-100cy per-wave-STREAM stall that
// survived 7 feed/schedule structures (per-stream fixed, not per-work).
// R14: amortize the stream stall over 2 COLUMNS PER WAVE (512 waves, grid
// 256 x 128). Both columns share one ds_read + one cvt set + one wait per
// round; the second column's rotations are perfect ILP filling the first's
// dependent-latency bubbles. x/out accessed as float2 (adjacent columns).
// Numerics identical to R13 (absmax 0.03125 vs 0.0925 threshold).

#define N_COLS   1024
#define PAIRS    256

typedef __attribute__((ext_vector_type(4))) float f32x4;

// Table layout: round r occupies bytes [r*1024, r*1024+1024); pair k's packed
// (c,s) __half2 at byte r*1024 + k*4. Lane l reads one b128 at +l*16 covering
// its pairs 4l..4l+3. Stride-16B across lanes: conflict-free.
__global__ __launch_bounds__(256) void rotmat_setup(const float* __restrict__ thetas,
                                                    __half2* __restrict__ cs16) {
    const int r = blockIdx.x;   // 0..510
    const int k = threadIdx.x;  // 0..255 (pair index)
    int pu = (k == 0) ? 0 : ((k - 1 - r + 1022) % 511) + 1;
    int pv = ((510 - k - r + 1022) % 511) + 1;
    int i = min(pu, pv), j = max(pu, pv);
    int t = i * 511 - (i * (i - 1)) / 2 + (j - i - 1);
    float s, c;
    sincosf(thetas[t], &s, &c);
    float sp = (pu < pv) ? s : -s;
    cs16[r * 256 + k] = __floats2half2_rn(c, sp);
}

// DPP wave-shift helpers (OOB lane keeps `old`).
__device__ __forceinline__ float dpp_shr1(float old, float src) {
    return __int_as_float(__builtin_amdgcn_update_dpp(
        __float_as_int(old), __float_as_int(src), 0x138, 0xF, 0xF, false));
}
__device__ __forceinline__ float dpp_shl1(float old, float src) {
    return __int_as_float(__builtin_amdgcn_update_dpp(
        __float_as_int(old), __float_as_int(src), 0x130, 0xF, 0xF, false));
}

__device__ __forceinline__ void glds16(const void* g, void* l) {
    __builtin_amdgcn_global_load_lds(
        (const __attribute__((address_space(1))) void*)g,
        (__attribute__((address_space(3))) void*)l, 16, 0, 0);
}

__device__ __forceinline__ __half2 f2h2(float f) {
    union { float f; __half2 h; } u; u.f = f; return u.h;
}

// One round, TWO columns, shared coeffs. DPP-early schedule: both columns'
// DPP-source rotations (pairs 3,0) first, 4 DPPs together, then the
// remaining rotations fill the DPP shadow. Pure SSA.
#define ROUND2(AA)                                                    \
    {                                                                 \
        __half2 P0 = f2h2((AA).x), P1 = f2h2((AA).y);                 \
        __half2 P2 = f2h2((AA).z), P3 = f2h2((AA).w);                 \
        float c0 = __low2float(P0), s0 = __high2float(P0);            \
        float c3 = __low2float(P3), s3 = __high2float(P3);            \
        float t3a = s3 * hiA[3], u3a = s3 * loA[3];                   \
        float l3a = fmaf(c3, loA[3], -t3a);                           \
        float h3a = fmaf(c3, hiA[3], u3a);                            \
        float t0a = s0 * hiA[0], u0a = s0 * loA[0];                   \
        float l0a = fmaf(c0, loA[0], -t0a);                           \
        float h0a = fmaf(c0, hiA[0], u0a);                            \
        float t3b = s3 * hiB[3], u3b = s3 * loB[3];                   \
        float l3b = fmaf(c3, loB[3], -t3b);                           \
        float h3b = fmaf(c3, hiB[3], u3b);                            \
        float t0b = s0 * hiB[0], u0b = s0 * loB[0];                   \
        float l0b = fmaf(c0, loB[0], -t0b);                           \
        float h0b = fmaf(c0, hiB[0], u0b);                            \
        float nlo0a = dpp_shr1(l0a, l3a);                             \
        float nhi3a = dpp_shl1(l3a, h0a);                             \
        float nlo0b = dpp_shr1(l0b, l3b);                             \
        float nhi3b = dpp_shl1(l3b, h0b);                             \
        float c1 = __low2float(P1), s1 = __high2float(P1);            \
        float c2 = __low2float(P2), s2 = __high2float(P2);            \
        float t1a = s1 * hiA[1], u1a = s1 * loA[1];                   \
        float l1a = fmaf(c1, loA[1], -t1a);                           \
        float h1a = fmaf(c1, hiA[1], u1a);                            \
        float t2a = s2 * hiA[2], u2a = s2 * loA[2];                   \
        float l2a = fmaf(c2, loA[2], -t2a);                           \
        float h2a = fmaf(c2, hiA[2], u2a);                            \
        float t1b = s1 * hiB[1], u1b = s1 * loB[1];                   \
        float l1b = fmaf(c1, loB[1], -t1b);                           \
        float h1b = fmaf(c1, hiB[1], u1b);                            \
        float t2b = s2 * hiB[2], u2b = s2 * loB[2];                   \
        float l2b = fmaf(c2, loB[2], -t2b);                           \
        float h2b = fmaf(c2, hiB[2], u2b);                            \
        float nlo1a = is0 ? h0a : l0a;                                \
        float nlo1b = is0 ? h0b : l0b;                                \
        loA[0] = nlo0a; loA[1] = nlo1a; loA[2] = l1a; loA[3] = l2a;   \
        hiA[0] = h1a; hiA[1] = h2a; hiA[2] = h3a; hiA[3] = nhi3a;     \
        loB[0] = nlo0b; loB[1] = nlo1b; loB[2] = l1b; loB[3] = l2b;   \
        hiB[0] = h1b; hiB[1] = h2b; hiB[2] = h3b; hiB[3] = nhi3b;     \
    }

// Volatile pinned ds_read_b128 with register base + immediate offset.
#define DSRD(dst, addr, imm)                                   \
    asm volatile("ds_read_b128 %0, %1 offset:%c2"              \
                 : "=v"(dst) : "v"(addr), "i"(imm))

// Counted lgkm waits that redefine the covered reg (dataflow ordering).
#define WL3(a) asm volatile("s_waitcnt lgkmcnt(3)" : "+v"(a))
#define WL2(a) asm volatile("s_waitcnt lgkmcnt(2)" : "+v"(a))
#define WL1(a) asm volatile("s_waitcnt lgkmcnt(1)" : "+v"(a))
#define WL0(a) asm volatile("s_waitcnt lgkmcnt(0)" : "+v"(a))

#define WAITV(n) asm volatile("s_waitcnt vmcnt(" #n ")" ::: "memory")
#define BAR()                               \
    __builtin_amdgcn_s_barrier();           \
    __builtin_amdgcn_sched_barrier(0)

// Stage chunk cix (16KB = 16 rounds x 1KB) into buffer bix; each of the 2
// waves covers 8KB (8 x 1KB glds16).
#define STAGE(cix, bix)                                              \
    {                                                                \
        const char* g_ = gsrc + (size_t)(cix)*16384;                 \
        char* l_ = lb + (size_t)(bix)*16384;                         \
        _Pragma("unroll")                                            \
        for (int j = 0; j < 8; ++j)                                  \
            glds16(g_ + j * 1024, l_ + j * 1024);                    \
    }

// 16 rounds, rolling 4-round-ahead reads (1 b128/round). Rounds 0..11 read
// same-chunk rounds 4..15 (ACUR); rounds 12..15 read next chunk 0..3 (ANXT).
#define CHUNK16(ACUR, ANXT)                                    \
    WL3(A0); ROUND2(A0) DSRD(A0, ACUR,  4 * 1024);             \
    WL3(A1); ROUND2(A1) DSRD(A1, ACUR,  5 * 1024);             \
    WL3(A2); ROUND2(A2) DSRD(A2, ACUR,  6 * 1024);             \
    WL3(A3); ROUND2(A3) DSRD(A3, ACUR,  7 * 1024);             \
    WL3(A0); ROUND2(A0) DSRD(A0, ACUR,  8 * 1024);             \
    WL3(A1); ROUND2(A1) DSRD(A1, ACUR,  9 * 1024);             \
    WL3(A2); ROUND2(A2) DSRD(A2, ACUR, 10 * 1024);             \
    WL3(A3); ROUND2(A3) DSRD(A3, ACUR, 11 * 1024);             \
    WL3(A0); ROUND2(A0) DSRD(A0, ACUR, 12 * 1024);             \
    WL3(A1); ROUND2(A1) DSRD(A1, ACUR, 13 * 1024);             \
    WL3(A2); ROUND2(A2) DSRD(A2, ACUR, 14 * 1024);             \
    WL3(A3); ROUND2(A3) DSRD(A3, ACUR, 15 * 1024);             \
    WL3(A0); ROUND2(A0) DSRD(A0, ANXT,  0 * 1024);             \
    WL3(A1); ROUND2(A1) DSRD(A1, ANXT,  1 * 1024);             \
    WL3(A2); ROUND2(A2) DSRD(A2, ANXT,  2 * 1024);             \
    WL3(A3); ROUND2(A3) DSRD(A3, ANXT,  3 * 1024);

template <bool TAB>
__global__ __launch_bounds__(128, 1) void rotmat_main(const float* __restrict__ x,
                                                      const float* __restrict__ thetas,
                                                      const __half2* __restrict__ cs16,
                                                      float* __restrict__ out) {
    __shared__ f32x4 tab[3 * 1024];  // 3 buffers x 16KB = 48KB

    const int lane = threadIdx.x & 63;
    const int wave = threadIdx.x >> 6;             // 0..1
    const int wid  = (blockIdx.x << 1) + wave;     // 0..511: columns 2wid, 2wid+1
    const int k0   = lane << 2;                    // first pair index of this lane
    const bool is0 = (lane == 0);

    const float2* x2  = reinterpret_cast<const float2*>(x);
    float2* o2        = reinterpret_cast<float2*>(out);

    float loA[4], hiA[4], loB[4], hiB[4];
#pragma unroll
    for (int m = 0; m < 4; ++m) {
        float2 vlo = x2[(k0 + m) * 512 + wid];
        float2 vhi = x2[(511 - k0 - m) * 512 + wid];
        loA[m] = vlo.x; loB[m] = vlo.y;
        hiA[m] = vhi.x; hiB[m] = vhi.y;
    }

    if constexpr (TAB) {
        const char* gsrc = (const char*)cs16 + (size_t)wave * 8192 + (size_t)lane * 16;
        char* lb = (char*)(&tab[0]) + (size_t)wave * 8192;
        unsigned ldsLane;
        {
            auto p3 = (__attribute__((address_space(3))) char*)(&tab[0]);
            ldsLane = (unsigned)(size_t)p3 + (unsigned)(lane * 16);
        }

        f32x4 A0, A1, A2, A3;  // ring: slot = round mod 4 (each = 4 x half2)

        // Prologue: stage chunks 0,1; both landed (and x loads); sync;
        // pre-issue reads for chunk 0 rounds 0..3.
        STAGE(0, 0)
        STAGE(1, 1)
        WAITV(0);
        BAR();
        {
            unsigned a0 = ldsLane;  // buffer 0 base
            DSRD(A0, a0, 0 * 1024);
            DSRD(A1, a0, 1 * 1024);
            DSRD(A2, a0, 2 * 1024);
            DSRD(A3, a0, 3 * 1024);
        }

        // Chunks 0..29 (rounds 0..479), staging chunk c+2 each.
        int bufCur = 0, bufNxt = 1, bufStg = 2;
        for (int c = 0; c < 30; ++c) {
            WAITV(0);   // own stage(c+1) landed (issued at top of c-1)
            BAR();      // all waves: stages visible; old-buffer reads retired
            STAGE(c + 2, bufStg)
            unsigned aCur = ldsLane + (unsigned)bufCur * 16384u;
            unsigned aNxt = ldsLane + (unsigned)bufNxt * 16384u;
            CHUNK16(aCur, aNxt)
            int t_ = bufCur; bufCur = bufNxt; bufNxt = bufStg; bufStg = t_;
        }

        // Chunk 30 (rounds 480..495): no staging (chunk 31 staged at c=29).
        {
            WAITV(0);   // stage(31) landed
            BAR();
            unsigned aCur = ldsLane + (unsigned)bufCur * 16384u;
            unsigned aNxt = ldsLane + (unsigned)bufNxt * 16384u;
            CHUNK16(aCur, aNxt)
            int t_ = bufCur; bufCur = bufNxt; bufNxt = bufStg; bufStg = t_;
        }

        // Chunk 31 tail: rounds 496..510 (15 real; pad round 511 never read).
        {
            unsigned aCur = ldsLane + (unsigned)bufCur * 16384u;
            WL3(A0); ROUND2(A0) DSRD(A0, aCur,  4 * 1024);
            WL3(A1); ROUND2(A1) DSRD(A1, aCur,  5 * 1024);
            WL3(A2); ROUND2(A2) DSRD(A2, aCur,  6 * 1024);
            WL3(A3); ROUND2(A3) DSRD(A3, aCur,  7 * 1024);
            WL3(A0); ROUND2(A0) DSRD(A0, aCur,  8 * 1024);
            WL3(A1); ROUND2(A1) DSRD(A1, aCur,  9 * 1024);
            WL3(A2); ROUND2(A2) DSRD(A2, aCur, 10 * 1024);
            WL3(A3); ROUND2(A3) DSRD(A3, aCur, 11 * 1024);
            WL3(A0); ROUND2(A0) DSRD(A0, aCur, 12 * 1024);
            WL3(A1); ROUND2(A1) DSRD(A1, aCur, 13 * 1024);
            WL3(A2); ROUND2(A2) DSRD(A2, aCur, 14 * 1024);
            WL3(A3); ROUND2(A3)   // round 507 (no more issues)
            WL2(A0); ROUND2(A0)   // round 508
            WL1(A1); ROUND2(A1)   // round 509
            WL0(A2); ROUND2(A2)   // round 510; ring drained
        }
    } else {
        // Fallback: compute schedule + sincos inline (no workspace table).
        int pu[4], pv[4];
#pragma unroll
        for (int m = 0; m < 4; ++m) {
            pu[m] = (k0 + m == 0) ? 0 : (k0 + m);
            pv[m] = 511 - (k0 + m);
        }
        for (int r = 0; r < 511; ++r) {
            float cc[4], ss[4];
#pragma unroll
            for (int m = 0; m < 4; ++m) {
                int i = min(pu[m], pv[m]), j = max(pu[m], pv[m]);
                int t = i * 511 - (i * (i - 1)) / 2 + (j - i - 1);
                float s, c;
                sincosf(thetas[t], &s, &c);
                cc[m] = c;
                ss[m] = (pu[m] < pv[m]) ? s : -s;
            }
#pragma unroll
            for (int q = 0; q < 2; ++q) {
                float* lo = q ? loB : loA;
                float* hi = q ? hiB : hiA;
                float t3 = ss[3] * hi[3], u3 = ss[3] * lo[3];
                float l3 = fmaf(cc[3], lo[3], -t3);
                float h3 = fmaf(cc[3], hi[3], u3);
                float t0 = ss[0] * hi[0], u0 = ss[0] * lo[0];
                float l0 = fmaf(cc[0], lo[0], -t0);
                float h0 = fmaf(cc[0], hi[0], u0);
                float nlo0 = dpp_shr1(l0, l3);
                float nhi3 = dpp_shl1(l3, h0);
                float t1 = ss[1] * hi[1], u1 = ss[1] * lo[1];
                float l1 = fmaf(cc[1], lo[1], -t1);
                float h1 = fmaf(cc[1], hi[1], u1);
                float t2 = ss[2] * hi[2], u2 = ss[2] * lo[2];
                float l2 = fmaf(cc[2], lo[2], -t2);
                float h2 = fmaf(cc[2], hi[2], u2);
                float nlo1 = is0 ? h0 : l0;
                lo[0] = nlo0; lo[1] = nlo1; lo[2] = l1; lo[3] = l2;
                hi[0] = h1; hi[1] = h2; hi[2] = h3; hi[3] = nhi3;
            }
#pragma unroll
            for (int m = 0; m < 4; ++m) {
                pu[m] = (k0 + m == 0) ? 0 : ((pu[m] == 1) ? 511 : pu[m] - 1);
                pv[m] = (pv[m] == 1) ? 511 : pv[m] - 1;
            }
        }
    }

    // After 511 shifts the position->row permutation is identity.
#pragma unroll
    for (int m = 0; m < 4; ++m) {
        o2[(k0 + m) * 512 + wid]       = make_float2(loA[m], loB[m]);
        o2[(511 - k0 - m) * 512 + wid] = make_float2(hiA[m], hiB[m]);
    }
}

extern "C" void kernel_launch(void* const* d_in, const int* in_sizes, int n_in,
                              void* d_out, int out_size, void* d_ws, size_t ws_size,
                              hipStream_t stream) {
    const float* x  = (const float*)d_in[0];
    const float* th = (const float*)d_in[1];
    float* out      = (float*)d_out;

    // Table: 512 rounds x 1KB (round 511 = pad; staged, never consumed).
    const size_t need = (size_t)512 * 1024;  // 512 KiB
    if (ws_size >= need) {
        __half2* cs16 = (__half2*)d_ws;
        rotmat_setup<<<511, PAIRS, 0, stream>>>(th, cs16);
        rotmat_main<true><<<256, 128, 0, stream>>>(x, th, cs16, out);
    } else {
        rotmat_main<false><<<256, 128, 0, stream>>>(x, th, nullptr, out);
    }
}

// Round 17
// 46.418 us; speedup vs baseline: 1.1613x; 1.1613x over previous
//
#include <hip/hip_runtime.h>
#include <hip/hip_fp16.h>

// RotMat forward: 511 rounds of 256 disjoint Givens rotations on rows of a
// [512, 1024] fp32 matrix (round-robin tournament schedule).
//
// Position-space: position k pairs with 511-k every round; between rounds a
// fixed cyclic shift. After 511 rounds the permutation is identity.
//
// Ladder: R0 177 -> R13 45.7us (DPP shifts, LDS triple-buffer glds16, pinned
// asm ds_read_b128 + counted lgkm, f16-packed coeffs). R14 regression (2
// cols/wave starved half the SIMDs). Fit: t ~ 5cy x inst/round + ~70cy fixed
// (solo wave, no TLP) -> lever is instruction count.
// R16 = R13 with the 8 v_cvt_f32_f16 per round deleted via v_fma_mix_f32
// (f16 coefficient read from packed half via op_sel, converted in-flight).
// R15's compile failure: neg_lo is a v_pk_* modifier; fma_mix negation is
// the standard -src prefix (applied to the f16 value before conversion).
// Numerically identical fma tree. ~29 -> ~21 inst/round.

#define N_COLS   1024
#define PAIRS    256

typedef __attribute__((ext_vector_type(4))) float f32x4;

// Table layout: round r occupies bytes [r*1024, r*1024+1024); pair k's packed
// (c,s) __half2 at byte r*1024 + k*4. Lane l reads one b128 at +l*16 covering
// its pairs 4l..4l+3. Stride-16B across lanes: conflict-free.
__global__ __launch_bounds__(256) void rotmat_setup(const float* __restrict__ thetas,
                                                    __half2* __restrict__ cs16) {
    const int r = blockIdx.x;   // 0..510
    const int k = threadIdx.x;  // 0..255 (pair index)
    int pu = (k == 0) ? 0 : ((k - 1 - r + 1022) % 511) + 1;
    int pv = ((510 - k - r + 1022) % 511) + 1;
    int i = min(pu, pv), j = max(pu, pv);
    int t = i * 511 - (i * (i - 1)) / 2 + (j - i - 1);
    float s, c;
    sincosf(thetas[t], &s, &c);
    float sp = (pu < pv) ? s : -s;
    cs16[r * 256 + k] = __floats2half2_rn(c, sp);
}

// DPP wave-shift helpers (OOB lane keeps `old`).
__device__ __forceinline__ float dpp_shr1(float old, float src) {
    return __int_as_float(__builtin_amdgcn_update_dpp(
        __float_as_int(old), __float_as_int(src), 0x138, 0xF, 0xF, false));
}
__device__ __forceinline__ float dpp_shl1(float old, float src) {
    return __int_as_float(__builtin_amdgcn_update_dpp(
        __float_as_int(old), __float_as_int(src), 0x130, 0xF, 0xF, false));
}

__device__ __forceinline__ void glds16(const void* g, void* l) {
    __builtin_amdgcn_global_load_lds(
        (const __attribute__((address_space(1))) void*)g,
        (__attribute__((address_space(3))) void*)l, 16, 0, 0);
}

// v_fma_mix_f32: f16 coefficient read directly from a half of the packed reg.
// P holds half2 (c = low half, s = high half) as a float-typed VGPR.
// op_sel_hi[i]=1 selects f16 source i; op_sel[i] picks which half.
// d = (-s) * x        (s from HIGH half, negated via -src; src2 = 0)
#define FMIX_SN(d, P, x)                                                      \
    asm("v_fma_mix_f32 %0, -%1, %2, 0 op_sel:[1,0,0] op_sel_hi:[1,0,0]"       \
        : "=v"(d) : "v"(P), "v"(x));
// d = s * x           (s from HIGH half; src2 = 0)
#define FMIX_SP(d, P, x)                                                      \
    asm("v_fma_mix_f32 %0, %1, %2, 0 op_sel:[1,0,0] op_sel_hi:[1,0,0]"        \
        : "=v"(d) : "v"(P), "v"(x));
// d = c * x + a       (c from LOW half)
#define FMIX_C(d, P, x, a)                                                    \
    asm("v_fma_mix_f32 %0, %1, %2, %3 op_sel:[0,0,0] op_sel_hi:[1,0,0]"       \
        : "=v"(d) : "v"(P), "v"(x), "v"(a));

// One round from one packed f32x4 (4 x half2). DPP-early schedule (R12/R13):
// pairs 3,0 (DPP-source producers) first, DPPs immediately after, pairs 1,2 +
// cndmask fill the DPP shadow. Pure SSA. Numerics identical to R13's
// fmaf(c,L,-(s*H)) / fmaf(c,H,s*L) trees (fpext f16->f32 is exact).
#define ROUND(AA)                                                  \
    {                                                              \
        float P0 = (AA).x, P1 = (AA).y, P2 = (AA).z, P3 = (AA).w;  \
        float t3, u3, l3, h3, t0, u0, l0, h0;                      \
        FMIX_SN(t3, P3, hi[3])                                     \
        FMIX_C(l3, P3, lo[3], t3)                                  \
        FMIX_SP(u3, P3, lo[3])                                     \
        FMIX_C(h3, P3, hi[3], u3)                                  \
        FMIX_SN(t0, P0, hi[0])                                     \
        FMIX_C(l0, P0, lo[0], t0)                                  \
        FMIX_SP(u0, P0, lo[0])                                     \
        FMIX_C(h0, P0, hi[0], u0)                                  \
        float nlo0 = dpp_shr1(l0, l3);                             \
        float nhi3 = dpp_shl1(l3, h0);                             \
        float t1, u1, l1, h1, t2, u2, l2, h2;                      \
        FMIX_SN(t1, P1, hi[1])                                     \
        FMIX_C(l1, P1, lo[1], t1)                                  \
        FMIX_SP(u1, P1, lo[1])                                     \
        FMIX_C(h1, P1, hi[1], u1)                                  \
        FMIX_SN(t2, P2, hi[2])                                     \
        FMIX_C(l2, P2, lo[2], t2)                                  \
        FMIX_SP(u2, P2, lo[2])                                     \
        FMIX_C(h2, P2, hi[2], u2)                                  \
        float nlo1 = is0 ? h0 : l0;                                \
        lo[0] = nlo0; lo[1] = nlo1; lo[2] = l1; lo[3] = l2;        \
        hi[0] = h1; hi[1] = h2; hi[2] = h3; hi[3] = nhi3;          \
    }

// Volatile pinned ds_read_b128 with register base + immediate offset.
#define DSRD(dst, addr, imm)                                   \
    asm volatile("ds_read_b128 %0, %1 offset:%c2"              \
                 : "=v"(dst) : "v"(addr), "i"(imm))

// Counted lgkm waits that redefine the covered reg (dataflow ordering).
#define WL3(a) asm volatile("s_waitcnt lgkmcnt(3)" : "+v"(a))
#define WL2(a) asm volatile("s_waitcnt lgkmcnt(2)" : "+v"(a))
#define WL1(a) asm volatile("s_waitcnt lgkmcnt(1)" : "+v"(a))
#define WL0(a) asm volatile("s_waitcnt lgkmcnt(0)" : "+v"(a))

#define WAITV(n) asm volatile("s_waitcnt vmcnt(" #n ")" ::: "memory")
#define BAR()                               \
    __builtin_amdgcn_s_barrier();           \
    __builtin_amdgcn_sched_barrier(0)

// Stage chunk cix (16KB = 16 rounds x 1KB) into buffer bix; wave covers its
// 4KB (4 x 1KB glds16).
#define STAGE(cix, bix)                                              \
    {                                                                \
        const char* g_ = gsrc + (size_t)(cix)*16384;                 \
        char* l_ = lb + (size_t)(bix)*16384;                         \
        _Pragma("unroll")                                            \
        for (int j = 0; j < 4; ++j)                                  \
            glds16(g_ + j * 1024, l_ + j * 1024);                    \
    }

// 16 rounds, rolling 4-round-ahead reads (1 b128/round). Rounds 0..11 read
// same-chunk rounds 4..15 (ACUR); rounds 12..15 read next chunk 0..3 (ANXT).
#define CHUNK16(ACUR, ANXT)                                    \
    WL3(A0); ROUND(A0) DSRD(A0, ACUR,  4 * 1024);              \
    WL3(A1); ROUND(A1) DSRD(A1, ACUR,  5 * 1024);              \
    WL3(A2); ROUND(A2) DSRD(A2, ACUR,  6 * 1024);              \
    WL3(A3); ROUND(A3) DSRD(A3, ACUR,  7 * 1024);              \
    WL3(A0); ROUND(A0) DSRD(A0, ACUR,  8 * 1024);              \
    WL3(A1); ROUND(A1) DSRD(A1, ACUR,  9 * 1024);              \
    WL3(A2); ROUND(A2) DSRD(A2, ACUR, 10 * 1024);              \
    WL3(A3); ROUND(A3) DSRD(A3, ACUR, 11 * 1024);              \
    WL3(A0); ROUND(A0) DSRD(A0, ACUR, 12 * 1024);              \
    WL3(A1); ROUND(A1) DSRD(A1, ACUR, 13 * 1024);              \
    WL3(A2); ROUND(A2) DSRD(A2, ACUR, 14 * 1024);              \
    WL3(A3); ROUND(A3) DSRD(A3, ACUR, 15 * 1024);              \
    WL3(A0); ROUND(A0) DSRD(A0, ANXT,  0 * 1024);              \
    WL3(A1); ROUND(A1) DSRD(A1, ANXT,  1 * 1024);              \
    WL3(A2); ROUND(A2) DSRD(A2, ANXT,  2 * 1024);              \
    WL3(A3); ROUND(A3) DSRD(A3, ANXT,  3 * 1024);

template <bool TAB>
__global__ __launch_bounds__(256, 1) void rotmat_main(const float* __restrict__ x,
                                                      const float* __restrict__ thetas,
                                                      const __half2* __restrict__ cs16,
                                                      float* __restrict__ out) {
    __shared__ f32x4 tab[3 * 1024];  // 3 buffers x 16KB = 48KB

    const int lane = threadIdx.x & 63;
    const int wave = threadIdx.x >> 6;
    const int col  = (blockIdx.x << 2) + wave;  // one column per wave
    const int k0   = lane << 2;                 // first pair index of this lane
    const bool is0 = (lane == 0);

    float lo[4], hi[4];
#pragma unroll
    for (int m = 0; m < 4; ++m) {
        lo[m] = x[(k0 + m) * N_COLS + col];
        hi[m] = x[(511 - k0 - m) * N_COLS + col];
    }

    if constexpr (TAB) {
        const char* gsrc = (const char*)cs16 + (size_t)wave * 4096 + (size_t)lane * 16;
        char* lb = (char*)(&tab[0]) + (size_t)wave * 4096;
        unsigned ldsLane;
        {
            auto p3 = (__attribute__((address_space(3))) char*)(&tab[0]);
            ldsLane = (unsigned)(size_t)p3 + (unsigned)(lane * 16);
        }

        f32x4 A0, A1, A2, A3;  // ring: slot = round mod 4 (each = 4 x half2)

        // Prologue: stage chunks 0,1; both landed; sync; pre-issue reads for
        // chunk 0 rounds 0..3.
        STAGE(0, 0)
        STAGE(1, 1)
        WAITV(0);
        BAR();
        {
            unsigned a0 = ldsLane;  // buffer 0 base
            DSRD(A0, a0, 0 * 1024);
            DSRD(A1, a0, 1 * 1024);
            DSRD(A2, a0, 2 * 1024);
            DSRD(A3, a0, 3 * 1024);
        }

        // Chunks 0..29 (rounds 0..479), staging chunk c+2 each.
        int bufCur = 0, bufNxt = 1, bufStg = 2;
        for (int c = 0; c < 30; ++c) {
            WAITV(0);   // own stage(c+1) landed (issued at top of c-1)
            BAR();      // all waves: stages visible; old-buffer reads retired
            STAGE(c + 2, bufStg)
            unsigned aCur = ldsLane + (unsigned)bufCur * 16384u;
            unsigned aNxt = ldsLane + (unsigned)bufNxt * 16384u;
            CHUNK16(aCur, aNxt)
            int t_ = bufCur; bufCur = bufNxt; bufNxt = bufStg; bufStg = t_;
        }

        // Chunk 30 (rounds 480..495): no staging (chunk 31 staged at c=29).
        {
            WAITV(0);   // stage(31) landed
            BAR();
            unsigned aCur = ldsLane + (unsigned)bufCur * 16384u;
            unsigned aNxt = ldsLane + (unsigned)bufNxt * 16384u;
            CHUNK16(aCur, aNxt)
            int t_ = bufCur; bufCur = bufNxt; bufNxt = bufStg; bufStg = t_;
        }

        // Chunk 31 tail: rounds 496..510 (15 real; pad round 511 never read).
        {
            unsigned aCur = ldsLane + (unsigned)bufCur * 16384u;
            WL3(A0); ROUND(A0) DSRD(A0, aCur,  4 * 1024);
            WL3(A1); ROUND(A1) DSRD(A1, aCur,  5 * 1024);
            WL3(A2); ROUND(A2) DSRD(A2, aCur,  6 * 1024);
            WL3(A3); ROUND(A3) DSRD(A3, aCur,  7 * 1024);
            WL3(A0); ROUND(A0) DSRD(A0, aCur,  8 * 1024);
            WL3(A1); ROUND(A1) DSRD(A1, aCur,  9 * 1024);
            WL3(A2); ROUND(A2) DSRD(A2, aCur, 10 * 1024);
            WL3(A3); ROUND(A3) DSRD(A3, aCur, 11 * 1024);
            WL3(A0); ROUND(A0) DSRD(A0, aCur, 12 * 1024);
            WL3(A1); ROUND(A1) DSRD(A1, aCur, 13 * 1024);
            WL3(A2); ROUND(A2) DSRD(A2, aCur, 14 * 1024);
            WL3(A3); ROUND(A3)   // round 507 (no more issues)
            WL2(A0); ROUND(A0)   // round 508
            WL1(A1); ROUND(A1)   // round 509
            WL0(A2); ROUND(A2)   // round 510; ring drained
        }
    } else {
        // Fallback: compute schedule + sincos inline (no workspace table).
        int pu[4], pv[4];
#pragma unroll
        for (int m = 0; m < 4; ++m) {
            pu[m] = (k0 + m == 0) ? 0 : (k0 + m);
            pv[m] = 511 - (k0 + m);
        }
        for (int r = 0; r < 511; ++r) {
            float cc[4], ss[4];
#pragma unroll
            for (int m = 0; m < 4; ++m) {
                int i = min(pu[m], pv[m]), j = max(pu[m], pv[m]);
                int t = i * 511 - (i * (i - 1)) / 2 + (j - i - 1);
                float s, c;
                sincosf(thetas[t], &s, &c);
                cc[m] = c;
                ss[m] = (pu[m] < pv[m]) ? s : -s;
            }
            {
                float t3 = ss[3] * hi[3], u3 = ss[3] * lo[3];
                float l3 = fmaf(cc[3], lo[3], -t3);
                float h3 = fmaf(cc[3], hi[3], u3);
                float t0 = ss[0] * hi[0], u0 = ss[0] * lo[0];
                float l0 = fmaf(cc[0], lo[0], -t0);
                float h0 = fmaf(cc[0], hi[0], u0);
                float nlo0 = dpp_shr1(l0, l3);
                float nhi3 = dpp_shl1(l3, h0);
                float t1 = ss[1] * hi[1], u1 = ss[1] * lo[1];
                float l1 = fmaf(cc[1], lo[1], -t1);
                float h1 = fmaf(cc[1], hi[1], u1);
                float t2 = ss[2] * hi[2], u2 = ss[2] * lo[2];
                float l2 = fmaf(cc[2], lo[2], -t2);
                float h2 = fmaf(cc[2], hi[2], u2);
                float nlo1 = is0 ? h0 : l0;
                lo[0] = nlo0; lo[1] = nlo1; lo[2] = l1; lo[3] = l2;
                hi[0] = h1; hi[1] = h2; hi[2] = h3; hi[3] = nhi3;
            }
#pragma unroll
            for (int m = 0; m < 4; ++m) {
                pu[m] = (k0 + m == 0) ? 0 : ((pu[m] == 1) ? 511 : pu[m] - 1);
                pv[m] = (pv[m] == 1) ? 511 : pv[m] - 1;
            }
        }
    }

    // After 511 shifts the position->row permutation is identity.
#pragma unroll
    for (int m = 0; m < 4; ++m) {
        out[(k0 + m) * N_COLS + col]       = lo[m];
        out[(511 - k0 - m) * N_COLS + col] = hi[m];
    }
}

extern "C" void kernel_launch(void* const* d_in, const int* in_sizes, int n_in,
                              void* d_out, int out_size, void* d_ws, size_t ws_size,
                              hipStream_t stream) {
    const float* x  = (const float*)d_in[0];
    const float* th = (const float*)d_in[1];
    float* out      = (float*)d_out;

    // Table: 512 rounds x 1KB (round 511 = pad; staged, never consumed).
    const size_t need = (size_t)512 * 1024;  // 512 KiB
    if (ws_size >= need) {
        __half2* cs16 = (__half2*)d_ws;
        rotmat_setup<<<511, PAIRS, 0, stream>>>(th, cs16);
        rotmat_main<true><<<N_COLS / 4, 256, 0, stream>>>(x, th, cs16, out);
    } else {
        rotmat_main<false><<<N_COLS / 4, 256, 0, stream>>>(x, th, nullptr, out);
    }
}